// Round 7
// baseline (1274.105 us; speedup 1.0000x reference)
//
#include <hip/hip_runtime.h>

#define SEQ    2048
#define NBATCH 8
#define EMB    1024
#define HD     64
#define NROWS  (NBATCH * SEQ)          /* 16384 */

// Documented interpretation, fp32 everywhere:
//   d_in[0] = embeddings [8,2048,1024] fp32
//   d_in[1] = Wq [1024,64] fp32 (x @ Wq)
//   d_in[2] = Wk [1024,64] fp32
//   d_in[3] = Wv [1024,64] fp32
//   d_out   = [8,2048,64] fp32   <-- the single variable changed this round

// ---------- scalar K,V projection ----------
__global__ __launch_bounds__(256) void kv_proj_scalar(const float* __restrict__ emb,
                                                      const float* __restrict__ Wk,
                                                      const float* __restrict__ Wv,
                                                      float* __restrict__ kv) {
  const int t = threadIdx.x;
  const int h = t & 63;
  const int rsub = t >> 6;
  const long row = (long)blockIdx.x * 4 + rsub;          // 0..16383
  const float* e = emb + row * EMB;
  float accK = 0.f, accV = 0.f;
  for (int d = 0; d < EMB; d++) {
    float ed = e[d];
    accK += ed * Wk[d * HD + h];
    accV += ed * Wv[d * HD + h];
  }
  kv[row * HD + h] = accK;
  kv[(long)NROWS * HD + row * HD + h] = accV;
}

// ---------- scalar attention: one 64-thread block per query row, textbook 2-pass ----------
__global__ __launch_bounds__(64) void attn_scalar(const float* __restrict__ emb,
                                                  const float* __restrict__ Wq,
                                                  const float* __restrict__ kv,
                                                  float* __restrict__ out) {
  __shared__ float S[SEQ];
  __shared__ float qsh[64];
  __shared__ float red[64];

  const int t = threadIdx.x;                 // 0..63
  const int row = blockIdx.x;                // 0..16383
  const int b = row >> 11;
  const int s = row & 2047;

  // q_h = emb_row . Wq[:,h]   (thread t owns h = t)
  const float* e = emb + (long)row * EMB;
  float q = 0.f;
  for (int d = 0; d < EMB; d++) q += e[d] * Wq[d * HD + t];
  qsh[t] = q;
  __syncthreads();

  const float* kbase = kv + ((long)b * SEQ) * HD;
  const float* vbase = kv + (long)NROWS * HD + ((long)b * SEQ) * HD;

  for (int j = t; j <= s; j += 64) {
    const float* kr = kbase + (long)j * HD;
    float acc = 0.f;
    for (int h = 0; h < HD; h++) acc += qsh[h] * kr[h];
    S[j] = acc * 0.125f;                     // 1/sqrt(64)
  }
  __syncthreads();

  float mx = -INFINITY;
  for (int j = t; j <= s; j += 64) mx = fmaxf(mx, S[j]);
  red[t] = mx;
  __syncthreads();
  for (int w = 32; w > 0; w >>= 1) {
    if (t < w) red[t] = fmaxf(red[t], red[t + w]);
    __syncthreads();
  }
  mx = red[0];
  __syncthreads();

  float sm = 0.f;
  for (int j = t; j <= s; j += 64) {
    float p = expf(S[j] - mx);
    S[j] = p;
    sm += p;
  }
  red[t] = sm;
  __syncthreads();
  for (int w = 32; w > 0; w >>= 1) {
    if (t < w) red[t] += red[t + w];
    __syncthreads();
  }
  const float l = red[0];
  __syncthreads();

  float o = 0.f;
  for (int j = 0; j <= s; j++) o += S[j] * vbase[(long)j * HD + t];

  out[(long)row * HD + t] = o / l;           // fp32 store — the changed variable
}

extern "C" void kernel_launch(void* const* d_in, const int* in_sizes, int n_in,
                              void* d_out, int out_size, void* d_ws, size_t ws_size,
                              hipStream_t stream) {
  const float* emb = (const float*)d_in[0];
  const float* wq  = (const float*)d_in[1];
  const float* wk  = (const float*)d_in[2];
  const float* wv  = (const float*)d_in[3];
  float* kv = (float*)d_ws;                   // 2 x 16384 x 64 fp32 = 8 MB

  hipLaunchKernelGGL(kv_proj_scalar, dim3(NROWS / 4), dim3(256), 0, stream, emb, wk, wv, kv);
  hipLaunchKernelGGL(attn_scalar,    dim3(NROWS),     dim3(64),  0, stream, emb, wq, kv,
                     (float*)d_out);
}

// Round 8
// 254.228 us; speedup vs baseline: 5.0117x; 5.0117x over previous
//
#include <hip/hip_runtime.h>

#define SEQ   2048
#define NBATCH 8
#define EMB   1024
#define HD    64
#define QKVSZ (NBATCH * SEQ * HD)   /* 1048576 elems per matrix */
#define WTSZ  (3 * HD * EMB)        /* 196608 */
#define LSTR  88                    /* LDS row stride in bf16 elems */

typedef __attribute__((ext_vector_type(8))) short bf16x8;
typedef __attribute__((ext_vector_type(4))) float f32x4;

__device__ inline unsigned short f2b(float f) {
  union { float f; unsigned int i; } u; u.f = f;
  unsigned int r = (u.i + 0x7FFFu + ((u.i >> 16) & 1u)) >> 16;  // RNE
  return (unsigned short)r;
}

// ---------------- W transpose + fp32->bf16: wt[m][c][d] = bf16(W[m][d][c]) ----------------
__global__ __launch_bounds__(256) void wtrans_kernel(const float* __restrict__ wq,
                                                     const float* __restrict__ wk,
                                                     const float* __restrict__ wv,
                                                     unsigned short* __restrict__ wt) {
  int i = blockIdx.x * 256 + threadIdx.x;       // 0 .. 196607
  int m = i >> 16;
  int c = (i >> 10) & 63;
  int d = i & 1023;
  const float* src = (m == 0) ? wq : ((m == 1) ? wk : wv);
  wt[i] = f2b(src[d * 64 + c]);
}

// ---------------- QKV projection: one wave = 16 rows x (3 mats x 64 cols) ----------------
__global__ __launch_bounds__(256) void qkv_proj_kernel(const float* __restrict__ emb,
                                                       const unsigned short* __restrict__ wt,
                                                       unsigned short* __restrict__ qkv) {
  const int t = threadIdx.x;
  const int wave = t >> 6;
  const int lane = t & 63;
  const int quad = lane >> 4;
  const int l16  = lane & 15;
  const int rt = blockIdx.x * 4 + wave;          // row tile 0..1023

  const float* arow = emb + ((size_t)(rt * 16 + l16)) * EMB + quad * 8;

  f32x4 acc[3][4];
#pragma unroll
  for (int m = 0; m < 3; m++)
#pragma unroll
    for (int n = 0; n < 4; n++) acc[m][n] = (f32x4){0.f, 0.f, 0.f, 0.f};

  for (int k = 0; k < EMB; k += 32) {
    f32x4 a0 = *(const f32x4*)(arow + k);
    f32x4 a1 = *(const f32x4*)(arow + k + 4);
    bf16x8 af;
#pragma unroll
    for (int j = 0; j < 4; j++) {
      af[j]     = (short)f2b(a0[j]);
      af[4 + j] = (short)f2b(a1[j]);
    }
#pragma unroll
    for (int m = 0; m < 3; m++) {
#pragma unroll
      for (int nt = 0; nt < 4; nt++) {
        bf16x8 bfr = *(const bf16x8*)(wt + m * (HD * EMB) + ((size_t)(nt * 16 + l16)) * EMB + k + quad * 8);
        acc[m][nt] = __builtin_amdgcn_mfma_f32_16x16x32_bf16(af, bfr, acc[m][nt], 0, 0, 0);
      }
    }
  }

#pragma unroll
  for (int m = 0; m < 3; m++)
#pragma unroll
    for (int nt = 0; nt < 4; nt++)
#pragma unroll
      for (int r = 0; r < 4; r++) {
        int row = rt * 16 + quad * 4 + r;        // C/D: row = quad*4+reg, col = l16
        qkv[(size_t)m * QKVSZ + (size_t)row * HD + nt * 16 + l16] = f2b(acc[m][nt][r]);
      }
}

// ---------------- Flash attention: block = 2 waves x 16 q-rows, 64-key tiles ----------------
__global__ __launch_bounds__(128) void attn_kernel(const unsigned short* __restrict__ qkv,
                                                   float* __restrict__ out) {
  __shared__ __align__(16) unsigned short Ksh[64 * LSTR];
  __shared__ __align__(16) unsigned short Vt[64 * LSTR];      // transposed: Vt[h][key]
  __shared__ __align__(16) unsigned short Psh[2 * 16 * LSTR];

  const int t = threadIdx.x;
  const int wave = t >> 6;
  const int lane = t & 63;
  const int quad = lane >> 4;
  const int l16  = lane & 15;
  const int qb = blockIdx.x;                      // 0..63 (32-row q tiles)
  const int b  = blockIdx.y;

  const unsigned short* qg = qkv;
  const unsigned short* kg = qkv + QKVSZ;
  const unsigned short* vg = qkv + 2 * QKVSZ;

  const int q0 = qb * 32 + wave * 16;             // this wave's 16 q rows

  const unsigned short* qptr = qg + ((size_t)(b * SEQ + q0 + l16)) * HD + quad * 8;
  const bf16x8 qf0 = *(const bf16x8*)qptr;        // d 0..31
  const bf16x8 qf1 = *(const bf16x8*)(qptr + 32); // d 32..63

  f32x4 o0 = {0,0,0,0}, o1 = {0,0,0,0}, o2 = {0,0,0,0}, o3 = {0,0,0,0};
  float mst[4] = {-INFINITY, -INFINITY, -INFINITY, -INFINITY};
  float lst[4] = {0.f, 0.f, 0.f, 0.f};

  const int kmax = (qb * 32 + 31) >> 6;           // inclusive last 64-key tile
  const float sc = 0.125f * 1.44269504088896f;    // 1/sqrt(64) * log2(e)

  unsigned short* pbase = Psh + wave * 16 * LSTR;

  for (int kb = 0; kb <= kmax; kb++) {
    __syncthreads();
    { // K tile, row-major [key][d]
      const bf16x8* src = (const bf16x8*)(kg + ((size_t)(b * SEQ + kb * 64)) * HD);
#pragma unroll
      for (int i = 0; i < 4; i++) {
        int idx = t + i * 128;                    // 0..511
        *(bf16x8*)(Ksh + (idx >> 3) * LSTR + (idx & 7) * 8) = src[idx];
      }
    }
    { // V tile transposed into Vt[h][key]
      int key = t >> 1, hb = (t & 1) * 32;
      const bf16x8* vsrc = (const bf16x8*)(vg + ((size_t)(b * SEQ + kb * 64 + key)) * HD + hb);
      bf16x8 vv[4];
#pragma unroll
      for (int i = 0; i < 4; i++) vv[i] = vsrc[i];
#pragma unroll
      for (int i = 0; i < 4; i++)
#pragma unroll
        for (int j = 0; j < 8; j++)
          Vt[(hb + i * 8 + j) * LSTR + key] = (unsigned short)vv[i][j];
    }
    __syncthreads();

    // S = Q K^T  (4 ktiles of 16 keys)
    f32x4 s[4];
#pragma unroll
    for (int kt = 0; kt < 4; kt++) {
      bf16x8 kf0 = *(const bf16x8*)(Ksh + (kt * 16 + l16) * LSTR + quad * 8);
      bf16x8 kf1 = *(const bf16x8*)(Ksh + (kt * 16 + l16) * LSTR + 32 + quad * 8);
      f32x4 z = {0.f, 0.f, 0.f, 0.f};
      z = __builtin_amdgcn_mfma_f32_16x16x32_bf16(qf0, kf0, z, 0, 0, 0);
      z = __builtin_amdgcn_mfma_f32_16x16x32_bf16(qf1, kf1, z, 0, 0, 0);
      s[kt] = z;
    }

    // scale + causal mask (C-layout: row = quad*4+r, col = kt*16+l16)
#pragma unroll
    for (int r = 0; r < 4; r++) {
      int rowg = q0 + quad * 4 + r;
#pragma unroll
      for (int kt = 0; kt < 4; kt++) {
        int col = kb * 64 + kt * 16 + l16;
        float v = s[kt][r] * sc;
        s[kt][r] = (col > rowg) ? -INFINITY : v;
      }
    }

    // online softmax (reduce across the 16-lane col group)
    float alpha[4];
#pragma unroll
    for (int r = 0; r < 4; r++) {
      float mx = fmaxf(fmaxf(s[0][r], s[1][r]), fmaxf(s[2][r], s[3][r]));
#pragma unroll
      for (int off = 1; off < 16; off <<= 1) mx = fmaxf(mx, __shfl_xor(mx, off, 64));
      float mnew = fmaxf(mst[r], mx);
      alpha[r] = exp2f(mst[r] - mnew);            // exp2(-inf) = 0 on first tile
      mst[r] = mnew;
    }
#pragma unroll
    for (int r = 0; r < 4; r++) {
      float sm = 0.f;
#pragma unroll
      for (int kt = 0; kt < 4; kt++) {
        float p = exp2f(s[kt][r] - mst[r]);       // masked: exp2(-inf) = 0
        s[kt][r] = p;
        sm += p;
      }
#pragma unroll
      for (int off = 1; off < 16; off <<= 1) sm += __shfl_xor(sm, off, 64);
      lst[r] = lst[r] * alpha[r] + sm;
    }
#pragma unroll
    for (int r = 0; r < 4; r++) { o0[r] *= alpha[r]; o1[r] *= alpha[r]; o2[r] *= alpha[r]; o3[r] *= alpha[r]; }

    // P (C-layout) -> LDS bf16, then re-read as A-operand layout
#pragma unroll
    for (int kt = 0; kt < 4; kt++)
#pragma unroll
      for (int r = 0; r < 4; r++)
        pbase[(quad * 4 + r) * LSTR + kt * 16 + l16] = f2b(s[kt][r]);
    __syncthreads();

    // O += P V : A = P[m=l16][k=key], B = V[k=key][n=h] from Vt[h][key]
#pragma unroll
    for (int kc = 0; kc < 2; kc++) {
      bf16x8 pf = *(const bf16x8*)(pbase + l16 * LSTR + kc * 32 + quad * 8);
      bf16x8 vf0 = *(const bf16x8*)(Vt + (0 + l16) * LSTR + kc * 32 + quad * 8);
      bf16x8 vf1 = *(const bf16x8*)(Vt + (16 + l16) * LSTR + kc * 32 + quad * 8);
      bf16x8 vf2 = *(const bf16x8*)(Vt + (32 + l16) * LSTR + kc * 32 + quad * 8);
      bf16x8 vf3 = *(const bf16x8*)(Vt + (48 + l16) * LSTR + kc * 32 + quad * 8);
      o0 = __builtin_amdgcn_mfma_f32_16x16x32_bf16(pf, vf0, o0, 0, 0, 0);
      o1 = __builtin_amdgcn_mfma_f32_16x16x32_bf16(pf, vf1, o1, 0, 0, 0);
      o2 = __builtin_amdgcn_mfma_f32_16x16x32_bf16(pf, vf2, o2, 0, 0, 0);
      o3 = __builtin_amdgcn_mfma_f32_16x16x32_bf16(pf, vf3, o3, 0, 0, 0);
    }
  }

#pragma unroll
  for (int r = 0; r < 4; r++) {
    float inv = 1.f / lst[r];
    int rowg = q0 + quad * 4 + r;
    size_t ob = ((size_t)(b * SEQ + rowg)) * HD + l16;
    out[ob + 0]  = o0[r] * inv;     // fp32 stores — the R7 fix
    out[ob + 16] = o1[r] * inv;
    out[ob + 32] = o2[r] * inv;
    out[ob + 48] = o3[r] * inv;
  }
}

extern "C" void kernel_launch(void* const* d_in, const int* in_sizes, int n_in,
                              void* d_out, int out_size, void* d_ws, size_t ws_size,
                              hipStream_t stream) {
  const float* emb = (const float*)d_in[0];
  const float* wq  = (const float*)d_in[1];
  const float* wk  = (const float*)d_in[2];
  const float* wv  = (const float*)d_in[3];
  unsigned short* ws  = (unsigned short*)d_ws;
  unsigned short* wt  = ws;              // 196608 bf16
  unsigned short* qkv = ws + WTSZ;       // 3 x 1048576 bf16

  hipLaunchKernelGGL(wtrans_kernel,   dim3(WTSZ / 256), dim3(256), 0, stream, wq, wk, wv, wt);
  hipLaunchKernelGGL(qkv_proj_kernel, dim3(256),        dim3(256), 0, stream, emb, wt, qkv);
  hipLaunchKernelGGL(attn_kernel,     dim3(64, 8),      dim3(128), 0, stream, qkv, (float*)d_out);
}

// Round 10
// 214.972 us; speedup vs baseline: 5.9268x; 1.1826x over previous
//
#include <hip/hip_runtime.h>

#define SEQ   2048
#define NBATCH 8
#define EMB   1024
#define HD    64
#define QKVSZ (NBATCH * SEQ * HD)   /* 1048576 elems per matrix */
#define WTSZ  (3 * HD * EMB)        /* 196608 */
#define LSTR  88                    /* LDS row stride in bf16 elems */

typedef __attribute__((ext_vector_type(8))) short bf16x8;
typedef __attribute__((ext_vector_type(4))) float f32x4;

__device__ inline unsigned short f2b(float f) {
  union { float f; unsigned int i; } u; u.f = f;
  unsigned int r = (u.i + 0x7FFFu + ((u.i >> 16) & 1u)) >> 16;  // RNE
  return (unsigned short)r;
}

// ---------------- W transpose (R8 proven version) ----------------
__global__ __launch_bounds__(256) void wtrans_kernel(const float* __restrict__ wq,
                                                     const float* __restrict__ wk,
                                                     const float* __restrict__ wv,
                                                     unsigned short* __restrict__ wt) {
  int i = blockIdx.x * 256 + threadIdx.x;       // 0 .. 196607
  int m = i >> 16;
  int c = (i >> 10) & 63;
  int d = i & 1023;
  const float* src = (m == 0) ? wq : ((m == 1) ? wk : wv);
  wt[i] = f2b(src[d * 64 + c]);
}

// ---------------- QKV projection: deep register prefetch (THE single R10 change) -------------
__global__ __launch_bounds__(256, 1) void qkv_proj_kernel(const float* __restrict__ emb,
                                                          const unsigned short* __restrict__ wt,
                                                          unsigned short* __restrict__ qkv) {
  const int t = threadIdx.x;
  const int wave = t >> 6;
  const int lane = t & 63;
  const int quad = lane >> 4;
  const int l16  = lane & 15;
  const int rt = blockIdx.x * 4 + wave;          // row tile 0..1023

  const float* arow = emb + ((size_t)(rt * 16 + l16)) * EMB + quad * 8;
  const unsigned short* wbase = wt + (size_t)l16 * EMB + quad * 8;

  f32x4 acc[3][4];
#pragma unroll
  for (int m = 0; m < 3; m++)
#pragma unroll
    for (int n = 0; n < 4; n++) acc[m][n] = (f32x4){0.f, 0.f, 0.f, 0.f};

  // A prefetch: depth 8 (iters 0..7)
  f32x4 a0p[8], a1p[8];
#pragma unroll
  for (int i = 0; i < 8; i++) {
    a0p[i] = *(const f32x4*)(arow + i * 32);
    a1p[i] = *(const f32x4*)(arow + i * 32 + 4);
  }
  // B prefetch: depth 3 (iters 0,1 preloaded)
  bf16x8 bp[3][12];
#pragma unroll
  for (int pi = 0; pi < 2; pi++)
#pragma unroll
    for (int m = 0; m < 3; m++)
#pragma unroll
      for (int nt = 0; nt < 4; nt++)
        bp[pi][m * 4 + nt] = *(const bf16x8*)(wbase + m * 65536 + (size_t)nt * 16 * EMB + pi * 32);

#pragma unroll
  for (int i = 0; i < 32; i++) {
    if (i + 2 < 32) {
#pragma unroll
      for (int m = 0; m < 3; m++)
#pragma unroll
        for (int nt = 0; nt < 4; nt++)
          bp[(i + 2) % 3][m * 4 + nt] =
              *(const bf16x8*)(wbase + m * 65536 + (size_t)nt * 16 * EMB + (i + 2) * 32);
    }
    f32x4 a0 = a0p[i & 7], a1 = a1p[i & 7];
    bf16x8 af;
#pragma unroll
    for (int j = 0; j < 4; j++) {
      af[j]     = (short)f2b(a0[j]);
      af[4 + j] = (short)f2b(a1[j]);
    }
    if (i + 8 < 32) {
      a0p[i & 7] = *(const f32x4*)(arow + (i + 8) * 32);
      a1p[i & 7] = *(const f32x4*)(arow + (i + 8) * 32 + 4);
    }
#pragma unroll
    for (int m = 0; m < 3; m++)
#pragma unroll
      for (int nt = 0; nt < 4; nt++)
        acc[m][nt] = __builtin_amdgcn_mfma_f32_16x16x32_bf16(af, bp[i % 3][m * 4 + nt], acc[m][nt], 0, 0, 0);
  }

#pragma unroll
  for (int m = 0; m < 3; m++)
#pragma unroll
    for (int nt = 0; nt < 4; nt++)
#pragma unroll
      for (int r = 0; r < 4; r++) {
        int row = rt * 16 + quad * 4 + r;        // C/D: row = quad*4+reg, col = l16
        qkv[(size_t)m * QKVSZ + (size_t)row * HD + nt * 16 + l16] = f2b(acc[m][nt][r]);
      }
}

// ---------------- Flash attention (R8 proven version, verbatim) ----------------
__global__ __launch_bounds__(128) void attn_kernel(const unsigned short* __restrict__ qkv,
                                                   float* __restrict__ out) {
  __shared__ __align__(16) unsigned short Ksh[64 * LSTR];
  __shared__ __align__(16) unsigned short Vt[64 * LSTR];      // transposed: Vt[h][key]
  __shared__ __align__(16) unsigned short Psh[2 * 16 * LSTR];

  const int t = threadIdx.x;
  const int wave = t >> 6;
  const int lane = t & 63;
  const int quad = lane >> 4;
  const int l16  = lane & 15;
  const int qb = blockIdx.x;                      // 0..63 (32-row q tiles)
  const int b  = blockIdx.y;

  const unsigned short* qg = qkv;
  const unsigned short* kg = qkv + QKVSZ;
  const unsigned short* vg = qkv + 2 * QKVSZ;

  const int q0 = qb * 32 + wave * 16;             // this wave's 16 q rows

  const unsigned short* qptr = qg + ((size_t)(b * SEQ + q0 + l16)) * HD + quad * 8;
  const bf16x8 qf0 = *(const bf16x8*)qptr;        // d 0..31
  const bf16x8 qf1 = *(const bf16x8*)(qptr + 32); // d 32..63

  f32x4 o0 = {0,0,0,0}, o1 = {0,0,0,0}, o2 = {0,0,0,0}, o3 = {0,0,0,0};
  float mst[4] = {-INFINITY, -INFINITY, -INFINITY, -INFINITY};
  float lst[4] = {0.f, 0.f, 0.f, 0.f};

  const int kmax = (qb * 32 + 31) >> 6;           // inclusive last 64-key tile
  const float sc = 0.125f * 1.44269504088896f;    // 1/sqrt(64) * log2(e)

  unsigned short* pbase = Psh + wave * 16 * LSTR;

  for (int kb = 0; kb <= kmax; kb++) {
    __syncthreads();
    { // K tile, row-major [key][d]
      const bf16x8* src = (const bf16x8*)(kg + ((size_t)(b * SEQ + kb * 64)) * HD);
#pragma unroll
      for (int i = 0; i < 4; i++) {
        int idx = t + i * 128;                    // 0..511
        *(bf16x8*)(Ksh + (idx >> 3) * LSTR + (idx & 7) * 8) = src[idx];
      }
    }
    { // V tile transposed into Vt[h][key]
      int key = t >> 1, hb = (t & 1) * 32;
      const bf16x8* vsrc = (const bf16x8*)(vg + ((size_t)(b * SEQ + kb * 64 + key)) * HD + hb);
      bf16x8 vv[4];
#pragma unroll
      for (int i = 0; i < 4; i++) vv[i] = vsrc[i];
#pragma unroll
      for (int i = 0; i < 4; i++)
#pragma unroll
        for (int j = 0; j < 8; j++)
          Vt[(hb + i * 8 + j) * LSTR + key] = (unsigned short)vv[i][j];
    }
    __syncthreads();

    // S = Q K^T  (4 ktiles of 16 keys)
    f32x4 s[4];
#pragma unroll
    for (int kt = 0; kt < 4; kt++) {
      bf16x8 kf0 = *(const bf16x8*)(Ksh + (kt * 16 + l16) * LSTR + quad * 8);
      bf16x8 kf1 = *(const bf16x8*)(Ksh + (kt * 16 + l16) * LSTR + 32 + quad * 8);
      f32x4 z = {0.f, 0.f, 0.f, 0.f};
      z = __builtin_amdgcn_mfma_f32_16x16x32_bf16(qf0, kf0, z, 0, 0, 0);
      z = __builtin_amdgcn_mfma_f32_16x16x32_bf16(qf1, kf1, z, 0, 0, 0);
      s[kt] = z;
    }

    // scale + causal mask (C-layout: row = quad*4+r, col = kt*16+l16)
#pragma unroll
    for (int r = 0; r < 4; r++) {
      int rowg = q0 + quad * 4 + r;
#pragma unroll
      for (int kt = 0; kt < 4; kt++) {
        int col = kb * 64 + kt * 16 + l16;
        float v = s[kt][r] * sc;
        s[kt][r] = (col > rowg) ? -INFINITY : v;
      }
    }

    // online softmax (reduce across the 16-lane col group)
    float alpha[4];
#pragma unroll
    for (int r = 0; r < 4; r++) {
      float mx = fmaxf(fmaxf(s[0][r], s[1][r]), fmaxf(s[2][r], s[3][r]));
#pragma unroll
      for (int off = 1; off < 16; off <<= 1) mx = fmaxf(mx, __shfl_xor(mx, off, 64));
      float mnew = fmaxf(mst[r], mx);
      alpha[r] = exp2f(mst[r] - mnew);            // exp2(-inf) = 0 on first tile
      mst[r] = mnew;
    }
#pragma unroll
    for (int r = 0; r < 4; r++) {
      float sm = 0.f;
#pragma unroll
      for (int kt = 0; kt < 4; kt++) {
        float p = exp2f(s[kt][r] - mst[r]);       // masked: exp2(-inf) = 0
        s[kt][r] = p;
        sm += p;
      }
#pragma unroll
      for (int off = 1; off < 16; off <<= 1) sm += __shfl_xor(sm, off, 64);
      lst[r] = lst[r] * alpha[r] + sm;
    }
#pragma unroll
    for (int r = 0; r < 4; r++) { o0[r] *= alpha[r]; o1[r] *= alpha[r]; o2[r] *= alpha[r]; o3[r] *= alpha[r]; }

    // P (C-layout) -> LDS bf16, then re-read as A-operand layout
#pragma unroll
    for (int kt = 0; kt < 4; kt++)
#pragma unroll
      for (int r = 0; r < 4; r++)
        pbase[(quad * 4 + r) * LSTR + kt * 16 + l16] = f2b(s[kt][r]);
    __syncthreads();

    // O += P V : A = P[m=l16][k=key], B = V[k=key][n=h] from Vt[h][key]
#pragma unroll
    for (int kc = 0; kc < 2; kc++) {
      bf16x8 pf = *(const bf16x8*)(pbase + l16 * LSTR + kc * 32 + quad * 8);
      bf16x8 vf0 = *(const bf16x8*)(Vt + (0 + l16) * LSTR + kc * 32 + quad * 8);
      bf16x8 vf1 = *(const bf16x8*)(Vt + (16 + l16) * LSTR + kc * 32 + quad * 8);
      bf16x8 vf2 = *(const bf16x8*)(Vt + (32 + l16) * LSTR + kc * 32 + quad * 8);
      bf16x8 vf3 = *(const bf16x8*)(Vt + (48 + l16) * LSTR + kc * 32 + quad * 8);
      o0 = __builtin_amdgcn_mfma_f32_16x16x32_bf16(pf, vf0, o0, 0, 0, 0);
      o1 = __builtin_amdgcn_mfma_f32_16x16x32_bf16(pf, vf1, o1, 0, 0, 0);
      o2 = __builtin_amdgcn_mfma_f32_16x16x32_bf16(pf, vf2, o2, 0, 0, 0);
      o3 = __builtin_amdgcn_mfma_f32_16x16x32_bf16(pf, vf3, o3, 0, 0, 0);
    }
  }

#pragma unroll
  for (int r = 0; r < 4; r++) {
    float inv = 1.f / lst[r];
    int rowg = q0 + quad * 4 + r;
    size_t ob = ((size_t)(b * SEQ + rowg)) * HD + l16;
    out[ob + 0]  = o0[r] * inv;
    out[ob + 16] = o1[r] * inv;
    out[ob + 32] = o2[r] * inv;
    out[ob + 48] = o3[r] * inv;
  }
}

extern "C" void kernel_launch(void* const* d_in, const int* in_sizes, int n_in,
                              void* d_out, int out_size, void* d_ws, size_t ws_size,
                              hipStream_t stream) {
  const float* emb = (const float*)d_in[0];
  const float* wq  = (const float*)d_in[1];
  const float* wk  = (const float*)d_in[2];
  const float* wv  = (const float*)d_in[3];
  unsigned short* ws  = (unsigned short*)d_ws;
  unsigned short* wt  = ws;              // 196608 bf16
  unsigned short* qkv = ws + WTSZ;       // 3 x 1048576 bf16

  hipLaunchKernelGGL(wtrans_kernel,   dim3(WTSZ / 256), dim3(256), 0, stream, wq, wk, wv, wt);
  hipLaunchKernelGGL(qkv_proj_kernel, dim3(256),        dim3(256), 0, stream, emb, wt, qkv);
  hipLaunchKernelGGL(attn_kernel,     dim3(64, 8),      dim3(128), 0, stream, qkv, (float*)d_out);
}

// Round 11
// 198.235 us; speedup vs baseline: 6.4272x; 1.0844x over previous
//
#include <hip/hip_runtime.h>

#define SEQ   2048
#define NBATCH 8
#define EMB   1024
#define HD    64
#define QKVSZ (NBATCH * SEQ * HD)   /* 1048576 elems per matrix */
#define WTSZ  (3 * HD * EMB)        /* 196608 */
#define LSTR  88                    /* proj-era LDS stride (unused here) */
#define KSTR  72
#define VSTR  72
#define PSTR  72                    /* >=64 + 16B-aligned (R9 bug was 40) */
#define PSLOT 1088                  /* floats per partial slot: 1024 O + 16 m + 16 l + pad */

typedef __attribute__((ext_vector_type(8))) short bf16x8;
typedef __attribute__((ext_vector_type(4))) float f32x4;

__device__ inline unsigned short f2b(float f) {
  union { float f; unsigned int i; } u; u.f = f;
  unsigned int r = (u.i + 0x7FFFu + ((u.i >> 16) & 1u)) >> 16;  // RNE
  return (unsigned short)r;
}

// ---------------- W transpose (R10 proven, verbatim) ----------------
__global__ __launch_bounds__(256) void wtrans_kernel(const float* __restrict__ wq,
                                                     const float* __restrict__ wk,
                                                     const float* __restrict__ wv,
                                                     unsigned short* __restrict__ wt) {
  int i = blockIdx.x * 256 + threadIdx.x;       // 0 .. 196607
  int m = i >> 16;
  int c = (i >> 10) & 63;
  int d = i & 1023;
  const float* src = (m == 0) ? wq : ((m == 1) ? wk : wv);
  wt[i] = f2b(src[d * 64 + c]);
}

// ---------------- QKV projection (R10 proven, verbatim) ----------------
__global__ __launch_bounds__(256, 1) void qkv_proj_kernel(const float* __restrict__ emb,
                                                          const unsigned short* __restrict__ wt,
                                                          unsigned short* __restrict__ qkv) {
  const int t = threadIdx.x;
  const int wave = t >> 6;
  const int lane = t & 63;
  const int quad = lane >> 4;
  const int l16  = lane & 15;
  const int rt = blockIdx.x * 4 + wave;          // row tile 0..1023

  const float* arow = emb + ((size_t)(rt * 16 + l16)) * EMB + quad * 8;
  const unsigned short* wbase = wt + (size_t)l16 * EMB + quad * 8;

  f32x4 acc[3][4];
#pragma unroll
  for (int m = 0; m < 3; m++)
#pragma unroll
    for (int n = 0; n < 4; n++) acc[m][n] = (f32x4){0.f, 0.f, 0.f, 0.f};

  f32x4 a0p[8], a1p[8];
#pragma unroll
  for (int i = 0; i < 8; i++) {
    a0p[i] = *(const f32x4*)(arow + i * 32);
    a1p[i] = *(const f32x4*)(arow + i * 32 + 4);
  }
  bf16x8 bp[3][12];
#pragma unroll
  for (int pi = 0; pi < 2; pi++)
#pragma unroll
    for (int m = 0; m < 3; m++)
#pragma unroll
      for (int nt = 0; nt < 4; nt++)
        bp[pi][m * 4 + nt] = *(const bf16x8*)(wbase + m * 65536 + (size_t)nt * 16 * EMB + pi * 32);

#pragma unroll
  for (int i = 0; i < 32; i++) {
    if (i + 2 < 32) {
#pragma unroll
      for (int m = 0; m < 3; m++)
#pragma unroll
        for (int nt = 0; nt < 4; nt++)
          bp[(i + 2) % 3][m * 4 + nt] =
              *(const bf16x8*)(wbase + m * 65536 + (size_t)nt * 16 * EMB + (i + 2) * 32);
    }
    f32x4 a0 = a0p[i & 7], a1 = a1p[i & 7];
    bf16x8 af;
#pragma unroll
    for (int j = 0; j < 4; j++) {
      af[j]     = (short)f2b(a0[j]);
      af[4 + j] = (short)f2b(a1[j]);
    }
    if (i + 8 < 32) {
      a0p[i & 7] = *(const f32x4*)(arow + (i + 8) * 32);
      a1p[i & 7] = *(const f32x4*)(arow + (i + 8) * 32 + 4);
    }
#pragma unroll
    for (int m = 0; m < 3; m++)
#pragma unroll
      for (int nt = 0; nt < 4; nt++)
        acc[m][nt] = __builtin_amdgcn_mfma_f32_16x16x32_bf16(af, bp[i % 3][m * 4 + nt], acc[m][nt], 0, 0, 0);
  }

#pragma unroll
  for (int m = 0; m < 3; m++)
#pragma unroll
    for (int nt = 0; nt < 4; nt++)
#pragma unroll
      for (int r = 0; r < 4; r++) {
        int row = rt * 16 + quad * 4 + r;        // C/D: row = quad*4+reg, col = l16
        qkv[(size_t)m * QKVSZ + (size_t)row * HD + nt * 16 + l16] = f2b(acc[m][nt][r]);
      }
}

// ---------------- Split-K flash attention: 1 wave/block, 16 q-rows, <=16-tile chunks --------
// grid.x = 192: idx<128 -> (qt=idx, c=0); idx>=128 -> (qt=64+idx-128, c=1)
__global__ __launch_bounds__(64, 2) void attn_split(const unsigned short* __restrict__ qkv,
                                                    float* __restrict__ part,
                                                    float* __restrict__ out) {
  __shared__ __align__(16) unsigned short Ksh[64 * KSTR];
  __shared__ __align__(16) unsigned short Vt[64 * VSTR];      // Vt[h][key]
  __shared__ __align__(16) unsigned short Psh[16 * PSTR];

  const int t = threadIdx.x;        // one wave
  const int quad = t >> 4;
  const int l16  = t & 15;
  const int idx = blockIdx.x;
  const int b   = blockIdx.y;
  const int qt  = (idx < 128) ? idx : (64 + (idx - 128));
  const int c   = (idx < 128) ? 0 : 1;
  const int q0  = qt * 16;
  const int kdiag = qt >> 2;                      // global diagonal tile
  const int t0 = c * 16;
  const int t1 = (c == 0) ? min(15, kdiag) : kdiag;

  const unsigned short* qg = qkv;
  const unsigned short* kg = qkv + QKVSZ;
  const unsigned short* vg = qkv + 2 * QKVSZ;

  const unsigned short* qptr = qg + ((size_t)(b * SEQ + q0 + l16)) * HD + quad * 8;
  const bf16x8 qf0 = *(const bf16x8*)qptr;        // d 0..31
  const bf16x8 qf1 = *(const bf16x8*)(qptr + 32); // d 32..63

  f32x4 o0 = {0,0,0,0}, o1 = {0,0,0,0}, o2 = {0,0,0,0}, o3 = {0,0,0,0};
  float mst[4] = {-INFINITY, -INFINITY, -INFINITY, -INFINITY};
  float lst[4] = {0.f, 0.f, 0.f, 0.f};
  const float sc = 0.125f * 1.44269504088896f;    // 1/sqrt(64) * log2(e)

  // prologue: prefetch tile t0 into registers
  bf16x8 kpre[8], vpre[8];
  {
    const bf16x8* ks = (const bf16x8*)(kg + ((size_t)(b * SEQ + t0 * 64)) * HD);
#pragma unroll
    for (int i = 0; i < 8; i++) kpre[i] = ks[t + i * 64];
    const bf16x8* vs = (const bf16x8*)(vg + ((size_t)(b * SEQ + t0 * 64 + t)) * HD);
#pragma unroll
    for (int i = 0; i < 8; i++) vpre[i] = vs[i];   // full row of key t0*64+t
  }

  for (int kb = t0; kb <= t1; kb++) {
    // stage prefetched tile into LDS
#pragma unroll
    for (int i = 0; i < 8; i++) {
      int u = t + i * 64;                          // 0..511 16B-units
      *(bf16x8*)(Ksh + (u >> 3) * KSTR + (u & 7) * 8) = kpre[i];
    }
#pragma unroll
    for (int i = 0; i < 8; i++)
#pragma unroll
      for (int j = 0; j < 8; j++)
        Vt[(i * 8 + j) * VSTR + t] = (unsigned short)vpre[i][j];  // Vt[h][key=t]
    __syncthreads();

    // prefetch next tile
    if (kb < t1) {
      const bf16x8* ks = (const bf16x8*)(kg + ((size_t)(b * SEQ + (kb + 1) * 64)) * HD);
#pragma unroll
      for (int i = 0; i < 8; i++) kpre[i] = ks[t + i * 64];
      const bf16x8* vs = (const bf16x8*)(vg + ((size_t)(b * SEQ + (kb + 1) * 64 + t)) * HD);
#pragma unroll
      for (int i = 0; i < 8; i++) vpre[i] = vs[i];
    }

    // S = Q K^T  (4 ktiles of 16 keys)
    f32x4 s[4];
#pragma unroll
    for (int kt = 0; kt < 4; kt++) {
      bf16x8 kf0 = *(const bf16x8*)(Ksh + (kt * 16 + l16) * KSTR + quad * 8);
      bf16x8 kf1 = *(const bf16x8*)(Ksh + (kt * 16 + l16) * KSTR + 32 + quad * 8);
      f32x4 z = {0.f, 0.f, 0.f, 0.f};
      z = __builtin_amdgcn_mfma_f32_16x16x32_bf16(qf0, kf0, z, 0, 0, 0);
      z = __builtin_amdgcn_mfma_f32_16x16x32_bf16(qf1, kf1, z, 0, 0, 0);
      s[kt] = z;
    }

    // scale; causal mask only on the diagonal tile
    if (kb == kdiag) {
#pragma unroll
      for (int r = 0; r < 4; r++) {
        int rowg = q0 + quad * 4 + r;
#pragma unroll
        for (int kt = 0; kt < 4; kt++) {
          int col = kb * 64 + kt * 16 + l16;
          float v = s[kt][r] * sc;
          s[kt][r] = (col > rowg) ? -INFINITY : v;
        }
      }
    } else {
#pragma unroll
      for (int r = 0; r < 4; r++)
#pragma unroll
        for (int kt = 0; kt < 4; kt++) s[kt][r] *= sc;
    }

    // online softmax (reduce across the 16-lane col group)
    float alpha[4];
#pragma unroll
    for (int r = 0; r < 4; r++) {
      float mx = fmaxf(fmaxf(s[0][r], s[1][r]), fmaxf(s[2][r], s[3][r]));
#pragma unroll
      for (int off = 1; off < 16; off <<= 1) mx = fmaxf(mx, __shfl_xor(mx, off, 64));
      float mnew = fmaxf(mst[r], mx);
      alpha[r] = exp2f(mst[r] - mnew);
      mst[r] = mnew;
    }
#pragma unroll
    for (int r = 0; r < 4; r++) {
      float sm = 0.f;
#pragma unroll
      for (int kt = 0; kt < 4; kt++) {
        float p = exp2f(s[kt][r] - mst[r]);
        s[kt][r] = p;
        sm += p;
      }
#pragma unroll
      for (int off = 1; off < 16; off <<= 1) sm += __shfl_xor(sm, off, 64);
      lst[r] = lst[r] * alpha[r] + sm;
    }
#pragma unroll
    for (int r = 0; r < 4; r++) { o0[r] *= alpha[r]; o1[r] *= alpha[r]; o2[r] *= alpha[r]; o3[r] *= alpha[r]; }

    // P (C-layout) -> LDS bf16
#pragma unroll
    for (int kt = 0; kt < 4; kt++)
#pragma unroll
      for (int r = 0; r < 4; r++)
        Psh[(quad * 4 + r) * PSTR + kt * 16 + l16] = f2b(s[kt][r]);
    __syncthreads();

    // O += P V
#pragma unroll
    for (int kc = 0; kc < 2; kc++) {
      bf16x8 pf = *(const bf16x8*)(Psh + l16 * PSTR + kc * 32 + quad * 8);
      bf16x8 vf0 = *(const bf16x8*)(Vt + (0 + l16) * VSTR + kc * 32 + quad * 8);
      bf16x8 vf1 = *(const bf16x8*)(Vt + (16 + l16) * VSTR + kc * 32 + quad * 8);
      bf16x8 vf2 = *(const bf16x8*)(Vt + (32 + l16) * VSTR + kc * 32 + quad * 8);
      bf16x8 vf3 = *(const bf16x8*)(Vt + (48 + l16) * VSTR + kc * 32 + quad * 8);
      o0 = __builtin_amdgcn_mfma_f32_16x16x32_bf16(pf, vf0, o0, 0, 0, 0);
      o1 = __builtin_amdgcn_mfma_f32_16x16x32_bf16(pf, vf1, o1, 0, 0, 0);
      o2 = __builtin_amdgcn_mfma_f32_16x16x32_bf16(pf, vf2, o2, 0, 0, 0);
      o3 = __builtin_amdgcn_mfma_f32_16x16x32_bf16(pf, vf3, o3, 0, 0, 0);
    }
    __syncthreads();
  }

  if (qt < 64) {  // single chunk: finalize directly
#pragma unroll
    for (int r = 0; r < 4; r++) {
      float inv = 1.f / lst[r];
      int rowg = q0 + quad * 4 + r;
      size_t ob = ((size_t)(b * SEQ + rowg)) * HD + l16;
      out[ob + 0]  = o0[r] * inv;
      out[ob + 16] = o1[r] * inv;
      out[ob + 32] = o2[r] * inv;
      out[ob + 48] = o3[r] * inv;
    }
  } else {        // write unnormalized partial + (m,l)
    float* ps = part + ((size_t)((b * 64 + (qt - 64)) * 2 + c)) * PSLOT;
#pragma unroll
    for (int r = 0; r < 4; r++) {
      int row = quad * 4 + r;
      ps[row * 64 + 0  + l16] = o0[r];
      ps[row * 64 + 16 + l16] = o1[r];
      ps[row * 64 + 32 + l16] = o2[r];
      ps[row * 64 + 48 + l16] = o3[r];
      if (l16 == 0) {
        ps[1024 + row] = mst[r];
        ps[1040 + row] = lst[r];
      }
    }
  }
}

// ---------------- merge two partials for qt in [64,128) ----------------
__global__ __launch_bounds__(64) void attn_merge(const float* __restrict__ part,
                                                 float* __restrict__ out) {
  const int h  = threadIdx.x;       // 0..63
  const int qx = blockIdx.x;        // 0..63 -> qt = 64+qx
  const int b  = blockIdx.y;
  const float* p0 = part + ((size_t)((b * 64 + qx) * 2 + 0)) * PSLOT;
  const float* p1 = p0 + PSLOT;
#pragma unroll 4
  for (int r = 0; r < 16; r++) {
    float m0 = p0[1024 + r], l0 = p0[1040 + r];
    float m1 = p1[1024 + r], l1 = p1[1040 + r];
    float M  = fmaxf(m0, m1);
    float e0 = exp2f(m0 - M), e1 = exp2f(m1 - M);
    float L  = l0 * e0 + l1 * e1;
    float o  = (p0[r * 64 + h] * e0 + p1[r * 64 + h] * e1) / L;
    out[((size_t)(b * SEQ + (64 + qx) * 16 + r)) * HD + h] = o;
  }
}

extern "C" void kernel_launch(void* const* d_in, const int* in_sizes, int n_in,
                              void* d_out, int out_size, void* d_ws, size_t ws_size,
                              hipStream_t stream) {
  const float* emb = (const float*)d_in[0];
  const float* wq  = (const float*)d_in[1];
  const float* wk  = (const float*)d_in[2];
  const float* wv  = (const float*)d_in[3];
  unsigned short* ws  = (unsigned short*)d_ws;
  unsigned short* wt  = ws;              // 196608 bf16
  unsigned short* qkv = ws + WTSZ;       // 3 x 1048576 bf16
  float* part = (float*)(ws + WTSZ + 3 * QKVSZ);   // 1024 slots x 1088 fp32 = 4.25 MB

  hipLaunchKernelGGL(wtrans_kernel,   dim3(WTSZ / 256), dim3(256), 0, stream, wq, wk, wv, wt);
  hipLaunchKernelGGL(qkv_proj_kernel, dim3(256),        dim3(256), 0, stream, emb, wt, qkv);
  hipLaunchKernelGGL(attn_split,      dim3(192, 8),     dim3(64),  0, stream, qkv, part, (float*)d_out);
  hipLaunchKernelGGL(attn_merge,      dim3(64, 8),      dim3(64),  0, stream, part, (float*)d_out);
}